// Round 9
// baseline (198.746 us; speedup 1.0000x reference)
//
#include <hip/hip_runtime.h>
#include <math.h>

// CBAM pillar kernel for MI355X (gfx950) — round 9: THREAD-per-pillar.
//
// R6/R8 falsified VALU-issue and ILP-stall theories for the wave-per-pillar
// design: its ~2262 cy/pillar floor is cross-lane orchestration (DPP /
// readlane hazards, lgkm drains).  R9 maps one pillar to one THREAD:
// ~11k plain VALU instr per 64-pillar wave, no cross-lane ops, no in-loop
// barriers.  Weights staged in LDS once/block; inner-loop weight reads are
// uniform-address ds_read_b128 broadcasts with immediate offsets.
// y0/y1/g in registers (loops fully unrolled); attc recomputed in the
// epilogue to keep peak VGPR ~180 (2 waves/SIMD, no spill).

#define CIN  5
#define CO   64

__device__ __forceinline__ float sgm(float x) {
  return 1.0f / (1.0f + __expf(-x));
}

// per-voxel: build packed pillar record pd[p] = {vf0[5], vf1[5], b0, b1}
__global__ __launch_bounds__(256) void pack_kernel(
    const float* __restrict__ vf, const int* __restrict__ vcoord,
    const int* __restrict__ unq_inv, float* __restrict__ pd, int n) {
  int i = blockIdx.x * blockDim.x + threadIdx.x;
  if (i >= n) return;
  int p = unq_inv[i];
  int slot = (i > 0 && unq_inv[i - 1] == p) ? 1 : 0;
  float* dst = pd + 12 * (size_t)p;
#pragma unroll
  for (int k = 0; k < 5; ++k) dst[5 * slot + k] = vf[5 * i + k];
  ((int*)dst)[10 + slot] = vcoord[4 * i + 1];
}

// LDS float offsets
#define OFF_W2   0      // 2048: W2 (32x64) row-major
#define OFF_WC1  2048   // 1024: Wc1 (64x16) row-major
#define OFF_WC2T 3072   // 1024: Wc2 transposed -> [ch*16 + j]
#define OFF_W1B  4096   // 256:  [j*8 + i] = W1[i][j] (i<5), b1[j] (i==5)
#define OFF_B2   4352   // 64
#define OFF_C0   4416   // 64:   c0[ch] = b2 + relu(b1) @ W2
#define OFF_BC1  4480   // 16
#define OFF_BC2  4496   // 64
#define OFF_WSMX 4560   // 64:   float2[32] clipped window sums per bin
#define OFF_WTAB 4624   // 16:   float2[8] conv taps, entry 7 = {0,0}
#define LDS_FLOATS 4640

__global__ __launch_bounds__(256) void cbam_kernel(
    const float* __restrict__ pd, const int* __restrict__ unq_cnt,
    const float* __restrict__ W1, const float* __restrict__ b1,
    const float* __restrict__ W2, const float* __restrict__ b2,
    const float* __restrict__ Wc1, const float* __restrict__ bc1,
    const float* __restrict__ Wc2, const float* __restrict__ bc2,
    const float* __restrict__ Wsp, const float* __restrict__ bsp,
    float* __restrict__ out, int U) {
  __shared__ __align__(16) float L[LDS_FLOATS];
  const int tid = threadIdx.x;

  // ---- stage weights to LDS (once per block)
  for (int i = tid; i < 2048; i += 256) L[OFF_W2 + i] = W2[i];
  for (int i = tid; i < 1024; i += 256) L[OFF_WC1 + i] = Wc1[i];
  for (int i = tid; i < 1024; i += 256) {
    int ch = i >> 4, j = i & 15;
    L[OFF_WC2T + i] = Wc2[j * 64 + ch];
  }
  {
    int j = tid >> 3, i = tid & 7;
    float v = 0.0f;
    if (i < 5) v = W1[i * 32 + j];
    else if (i == 5) v = b1[j];
    L[OFF_W1B + tid] = v;
  }
  if (tid < 64) L[OFF_B2 + tid] = b2[tid];
  if (tid < 64) L[OFF_BC2 + tid] = bc2[tid];
  if (tid < 16) L[OFF_BC1 + tid] = bc1[tid];
  __syncthreads();
  if (tid < 64) {          // c0[ch] = b2[ch] + sum_j relu(b1[j]) W2[j][ch]
    float c = L[OFF_B2 + tid];
    for (int j = 0; j < 32; ++j)
      c += fmaxf(L[OFF_W1B + j * 8 + 5], 0.0f) * L[OFF_W2 + j * 64 + tid];
    L[OFF_C0 + tid] = c;
  }
  if (tid < 32) {          // clipped conv-window sums per output bin
    float sm = 0.0f, sx = 0.0f;
    for (int k = 0; k < 7; ++k)
      if ((unsigned)(tid + k - 3) < 32u) { sm += Wsp[k]; sx += Wsp[7 + k]; }
    L[OFF_WSMX + 2 * tid] = sm;
    L[OFF_WSMX + 2 * tid + 1] = sx;
  }
  if (tid < 8) {
    float a = 0.0f, bb = 0.0f;
    if (tid < 7) { a = Wsp[tid]; bb = Wsp[7 + tid]; }
    L[OFF_WTAB + 2 * tid] = a;
    L[OFF_WTAB + 2 * tid + 1] = bb;
  }
  __syncthreads();

  const int p = blockIdx.x * 256 + tid;
  if (p >= U) return;      // no barriers after this point

  // ---- load packed pillar record (3 independent dwordx4, coalesced-ish)
  const float4* __restrict__ pdv = (const float4*)pd;
  const float4 A = pdv[3 * (size_t)p];
  const float4 B = pdv[3 * (size_t)p + 1];
  const float4 Cq = pdv[3 * (size_t)p + 2];
  const int cnt = unq_cnt[p];
  const bool has2 = (cnt >= 2);
  float vf0[5] = {A.x, A.y, A.z, A.w, B.x};
  float vf1[5] = {B.y, B.z, B.w, Cq.x, Cq.y};
#pragma unroll
  for (int i = 0; i < 5; ++i) vf1[i] = has2 ? vf1[i] : vf0[i];
  const int b0  = __builtin_bit_cast(int, Cq.z) & 31;
  const int b1e = has2 ? (__builtin_bit_cast(int, Cq.w) & 31) : 64;  // 64: no match

  const float4* L4 = (const float4*)L;

  // ---- up-dimension MLP: y0/y1[64] in registers
  float y0[64], y1[64];
#pragma unroll
  for (int cb = 0; cb < 16; ++cb) {
    float4 bb = L4[OFF_B2 / 4 + cb];
    y0[4 * cb] = bb.x; y0[4 * cb + 1] = bb.y;
    y0[4 * cb + 2] = bb.z; y0[4 * cb + 3] = bb.w;
    y1[4 * cb] = bb.x; y1[4 * cb + 1] = bb.y;
    y1[4 * cb + 2] = bb.z; y1[4 * cb + 3] = bb.w;
  }
  for (int j = 0; j < 32; ++j) {       // rolled: body ~145 instr
    float4 wA = L4[OFF_W1B / 4 + 2 * j];
    float4 wB = L4[OFF_W1B / 4 + 2 * j + 1];
    float h0 = wB.y + vf0[0] * wA.x + vf0[1] * wA.y + vf0[2] * wA.z +
               vf0[3] * wA.w + vf0[4] * wB.x;
    float h1 = wB.y + vf1[0] * wA.x + vf1[1] * wA.y + vf1[2] * wA.z +
               vf1[3] * wA.w + vf1[4] * wB.x;
    h0 = fmaxf(h0, 0.0f);
    h1 = fmaxf(h1, 0.0f);
#pragma unroll
    for (int cb = 0; cb < 16; ++cb) {
      float4 w = L4[OFF_W2 / 4 + j * 16 + cb];
      y0[4 * cb]     += h0 * w.x; y0[4 * cb + 1] += h0 * w.y;
      y0[4 * cb + 2] += h0 * w.z; y0[4 * cb + 3] += h0 * w.w;
      y1[4 * cb]     += h1 * w.x; y1[4 * cb + 1] += h1 * w.y;
      y1[4 * cb + 2] += h1 * w.z; y1[4 * cb + 3] += h1 * w.w;
    }
  }

  // ---- pooled stats + channel-MLP layer 1 (streamed, no avg/mx arrays)
  float ha[16], hm[16];
#pragma unroll
  for (int jb = 0; jb < 4; ++jb) {
    float4 bb = L4[OFF_BC1 / 4 + jb];
    ha[4 * jb] = bb.x; ha[4 * jb + 1] = bb.y;
    ha[4 * jb + 2] = bb.z; ha[4 * jb + 3] = bb.w;
    hm[4 * jb] = bb.x; hm[4 * jb + 1] = bb.y;
    hm[4 * jb + 2] = bb.z; hm[4 * jb + 3] = bb.w;
  }
  const float kf = has2 ? 30.0f : 31.0f;   // 32 - nocc
  const float inv32 = 1.0f / 32.0f;
#pragma unroll
  for (int ch = 0; ch < 64; ++ch) {
    float c0v = L[OFF_C0 + ch];
    float y1s = has2 ? y1[ch] : 0.0f;
    float sumy = y0[ch] + y1s;
    float maxy = fmaxf(y0[ch], y1[ch]);        // y1==y0 when !has2
    float avg = fmaf(c0v, kf, sumy) * inv32;
    float mxv = fmaxf(maxy, c0v);
#pragma unroll
    for (int jb = 0; jb < 4; ++jb) {
      float4 w = L4[OFF_WC1 / 4 + ch * 4 + jb];
      ha[4 * jb]     += avg * w.x; ha[4 * jb + 1] += avg * w.y;
      ha[4 * jb + 2] += avg * w.z; ha[4 * jb + 3] += avg * w.w;
      hm[4 * jb]     += mxv * w.x; hm[4 * jb + 1] += mxv * w.y;
      hm[4 * jb + 2] += mxv * w.z; hm[4 * jb + 3] += mxv * w.w;
    }
  }
  float g[16];
#pragma unroll
  for (int j = 0; j < 16; ++j)
    g[j] = fmaxf(ha[j], 0.0f) + fmaxf(hm[j], 0.0f);

  // ---- channel attention + bin-column reductions (attc NOT stored)
  float sc = 0.0f, mc = -3.0e38f;
  float sy0 = 0.0f, my0 = -3.0e38f, sy1 = 0.0f, my1 = -3.0e38f;
#pragma unroll
  for (int ch = 0; ch < 64; ++ch) {
    float4 wa = L4[OFF_WC2T / 4 + ch * 4 + 0];
    float4 wb = L4[OFF_WC2T / 4 + ch * 4 + 1];
    float4 wc = L4[OFF_WC2T / 4 + ch * 4 + 2];
    float4 wd = L4[OFF_WC2T / 4 + ch * 4 + 3];
    float q0 = g[0] * wa.x + g[1] * wa.y + g[2] * wa.z + g[3] * wa.w;
    float q1 = g[4] * wb.x + g[5] * wb.y + g[6] * wb.z + g[7] * wb.w;
    float q2 = g[8] * wc.x + g[9] * wc.y + g[10] * wc.z + g[11] * wc.w;
    float q3 = g[12] * wd.x + g[13] * wd.y + g[14] * wd.z + g[15] * wd.w;
    float pre = 2.0f * L[OFF_BC2 + ch] + (q0 + q1) + (q2 + q3);
    float attc = sgm(pre);
    float c0v = L[OFF_C0 + ch];
    float pc0 = attc * c0v, py0 = attc * y0[ch], py1 = attc * y1[ch];
    sc += pc0;  mc = fmaxf(mc, pc0);
    sy0 += py0; my0 = fmaxf(my0, py0);
    sy1 += py1; my1 = fmaxf(my1, py1);
  }

  // ---- analytic bin-attention conv over 32 bins (rolled)
  const float inv64 = 1.0f / 64.0f;
  const float Mn = sc * inv64, Mx = mc;
  const float dm0 = (sy0 - sc) * inv64, dx0 = my0 - mc;
  const float dm1 = (sy1 - sc) * inv64, dx1 = my1 - mc;
  const float bspr = bsp[0];
  const float2* Lws = (const float2*)(L + OFF_WSMX);
  const float2* Lwt = (const float2*)(L + OFF_WTAB);
  float maxE = -3.0e38f, minE = 3.0e38f, sv0 = 0.0f, sv1 = 0.0f;
  for (int b = 0; b < 32; ++b) {
    float2 ws = Lws[b];                      // uniform -> broadcast
    float acc = bspr + Mn * ws.x + Mx * ws.y;
    int k0 = b0 - b + 3; k0 = ((unsigned)k0 <= 6u) ? k0 : 7;
    int k1 = b1e - b + 3; k1 = ((unsigned)k1 <= 6u) ? k1 : 7;
    float2 w0 = Lwt[k0];                     // <=8 distinct addrs, distinct banks
    float2 w1v = Lwt[k1];
    acc += dm0 * w0.x + dx0 * w0.y + dm1 * w1v.x + dx1 * w1v.y;
    bool o0 = (b == b0), o1 = (b == b1e);
    bool oc = o0 || o1;
    maxE = fmaxf(maxE, oc ? -3.0e38f : acc);
    minE = fminf(minE, oc ?  3.0e38f : acc);
    sv0 = o0 ? acc : sv0;
    sv1 = o1 ? acc : sv1;
  }
  const float sig0 = sgm(sv0);
  const float sig1 = has2 ? sgm(sv1) : sig0;
  const float sEv = sgm(maxE), sIv = sgm(minE);

  // ---- epilogue: recompute attc, final max over bins, store
  float4* outv = (float4*)out;
  float* __restrict__ omask = out + (size_t)U * CO;
#pragma unroll
  for (int cb = 0; cb < 16; ++cb) {
    float rr[4];
#pragma unroll
    for (int i = 0; i < 4; ++i) {
      int ch = 4 * cb + i;
      float4 wa = L4[OFF_WC2T / 4 + ch * 4 + 0];
      float4 wb = L4[OFF_WC2T / 4 + ch * 4 + 1];
      float4 wc = L4[OFF_WC2T / 4 + ch * 4 + 2];
      float4 wd = L4[OFF_WC2T / 4 + ch * 4 + 3];
      float q0 = g[0] * wa.x + g[1] * wa.y + g[2] * wa.z + g[3] * wa.w;
      float q1 = g[4] * wb.x + g[5] * wb.y + g[6] * wb.z + g[7] * wb.w;
      float q2 = g[8] * wc.x + g[9] * wc.y + g[10] * wc.z + g[11] * wc.w;
      float q3 = g[12] * wd.x + g[13] * wd.y + g[14] * wd.z + g[15] * wd.w;
      float pre = 2.0f * L[OFF_BC2 + ch] + (q0 + q1) + (q2 + q3);
      float attc = sgm(pre);
      float c0v = L[OFF_C0 + ch];
      float sel = (c0v >= 0.0f) ? sEv : sIv;
      float m = fmaxf(fmaxf(y0[ch] * sig0, y1[ch] * sig1), c0v * sel);
      rr[i] = attc * m;
    }
    float4 r;
    r.x = rr[0]; r.y = rr[1]; r.z = rr[2]; r.w = rr[3];
    outv[(size_t)p * 16 + cb] = r;
  }
  omask[p] = has2 ? 1.0f : 0.0f;
}

extern "C" void kernel_launch(void* const* d_in, const int* in_sizes, int n_in,
                              void* d_out, int out_size, void* d_ws, size_t ws_size,
                              hipStream_t stream) {
  const float* vf      = (const float*)d_in[0];
  const int*   vcoord  = (const int*)d_in[1];
  // d_in[2] = unq_coords (unused: identity)
  const int*   unq_inv = (const int*)d_in[3];
  const int*   unq_cnt = (const int*)d_in[4];
  const float* W1  = (const float*)d_in[5];
  const float* b1  = (const float*)d_in[6];
  const float* W2  = (const float*)d_in[7];
  const float* b2  = (const float*)d_in[8];
  const float* Wc1 = (const float*)d_in[9];
  const float* bc1 = (const float*)d_in[10];
  const float* Wc2 = (const float*)d_in[11];
  const float* bc2 = (const float*)d_in[12];
  const float* Wsp = (const float*)d_in[13];
  const float* bsp = (const float*)d_in[14];

  const int N = in_sizes[3];   // voxels
  const int U = in_sizes[4];   // pillars

  float* pd = (float*)d_ws;    // 12 floats per pillar (4.8 MB @ U=100k)

  pack_kernel<<<(N + 255) / 256, 256, 0, stream>>>(vf, vcoord, unq_inv, pd, N);

  const int blocks = (U + 255) / 256;   // one THREAD per pillar
  cbam_kernel<<<blocks, 256, 0, stream>>>(
      pd, unq_cnt, W1, b1, W2, b2, Wc1, bc1, Wc2, bc2,
      Wsp, bsp, (float*)d_out, U);
}

// Round 10
// 168.266 us; speedup vs baseline: 1.1811x; 1.1811x over previous
//
#include <hip/hip_runtime.h>
#include <math.h>

// CBAM pillar kernel for MI355X (gfx950) — round 10: 2 THREADS per pillar.
//
// R9 (thread-per-pillar) failed on scratch spills (WRITE 25.8->86MB) and a
// 391-block grid (~1 block/CU).  R10 splits each pillar across a LANE PAIR
// (even lane: channels 0-31, odd: 32-63): register arrays halve (no spill),
// grid doubles to 782 blocks, and all pair communication is one DPP
// quad_perm exchange (VALU) — still zero ds_bpermute / readlane / barriers
// in the worker phase.  LDS weight reads present <=2 distinct addresses per
// instruction -> broadcast, conflict-free.

#define CIN  5
#define CO   64

__device__ __forceinline__ float sgm(float x) {
  return 1.0f / (1.0f + __expf(-x));
}
// value held by the other lane of the pair (quad_perm [1,0,3,2])
__device__ __forceinline__ float pairx(float x) {
  int t = __builtin_amdgcn_update_dpp(0, __builtin_bit_cast(int, x),
                                      0xB1, 0xf, 0xf, true);
  return __builtin_bit_cast(float, t);
}

// per-voxel: build packed pillar record pd[p] = {vf0[5], vf1[5], b0, b1}
__global__ __launch_bounds__(256) void pack_kernel(
    const float* __restrict__ vf, const int* __restrict__ vcoord,
    const int* __restrict__ unq_inv, float* __restrict__ pd, int n) {
  int i = blockIdx.x * blockDim.x + threadIdx.x;
  if (i >= n) return;
  int p = unq_inv[i];
  int slot = (i > 0 && unq_inv[i - 1] == p) ? 1 : 0;
  float* dst = pd + 12 * (size_t)p;
#pragma unroll
  for (int k = 0; k < 5; ++k) dst[5 * slot + k] = vf[5 * i + k];
  ((int*)dst)[10 + slot] = vcoord[4 * i + 1];
}

// LDS float offsets
#define OFF_W2   0      // 2048: W2 (32x64) row-major [j*64 + ch]
#define OFF_WC1  2048   // 1024: Wc1 row-major [ch*16 + j]
#define OFF_WC2T 3072   // 1024: Wc2 transposed [ch*16 + j]
#define OFF_W1B  4096   // 256:  [j*8 + i] = W1[i][j] (i<5), b1[j] (i==5)
#define OFF_B2   4352   // 64
#define OFF_C0   4416   // 64:   c0[ch] = b2 + relu(b1) @ W2
#define OFF_BC1  4480   // 16
#define OFF_BC2  4496   // 64
#define OFF_WSMX 4560   // 64:   float2[32] clipped window sums per bin
#define OFF_WTAB 4624   // 16:   float2[8] conv taps, entry 7 = {0,0}
#define LDS_FLOATS 4640

__global__ __launch_bounds__(256) void cbam_kernel(
    const float* __restrict__ pd, const int* __restrict__ unq_cnt,
    const float* __restrict__ W1, const float* __restrict__ b1,
    const float* __restrict__ W2, const float* __restrict__ b2,
    const float* __restrict__ Wc1, const float* __restrict__ bc1,
    const float* __restrict__ Wc2, const float* __restrict__ bc2,
    const float* __restrict__ Wsp, const float* __restrict__ bsp,
    float* __restrict__ out, int U) {
  __shared__ __align__(16) float L[LDS_FLOATS];
  const int tid = threadIdx.x;

  // ---- stage weights to LDS (once per block)
  for (int i = tid; i < 2048; i += 256) L[OFF_W2 + i] = W2[i];
  for (int i = tid; i < 1024; i += 256) L[OFF_WC1 + i] = Wc1[i];
  for (int i = tid; i < 1024; i += 256) {
    int ch = i >> 4, j = i & 15;
    L[OFF_WC2T + i] = Wc2[j * 64 + ch];
  }
  {
    int j = tid >> 3, i = tid & 7;
    float v = 0.0f;
    if (i < 5) v = W1[i * 32 + j];
    else if (i == 5) v = b1[j];
    L[OFF_W1B + tid] = v;
  }
  if (tid < 64) L[OFF_B2 + tid] = b2[tid];
  if (tid < 64) L[OFF_BC2 + tid] = bc2[tid];
  if (tid < 16) L[OFF_BC1 + tid] = bc1[tid];
  __syncthreads();
  if (tid < 64) {          // c0[ch] = b2[ch] + sum_j relu(b1[j]) W2[j][ch]
    float c = L[OFF_B2 + tid];
    for (int j = 0; j < 32; ++j)
      c += fmaxf(L[OFF_W1B + j * 8 + 5], 0.0f) * L[OFF_W2 + j * 64 + tid];
    L[OFF_C0 + tid] = c;
  }
  if (tid < 32) {          // clipped conv-window sums per output bin
    float sm = 0.0f, sx = 0.0f;
    for (int k = 0; k < 7; ++k)
      if ((unsigned)(tid + k - 3) < 32u) { sm += Wsp[k]; sx += Wsp[7 + k]; }
    L[OFF_WSMX + 2 * tid] = sm;
    L[OFF_WSMX + 2 * tid + 1] = sx;
  }
  if (tid < 8) {
    float a = 0.0f, bb = 0.0f;
    if (tid < 7) { a = Wsp[tid]; bb = Wsp[7 + tid]; }
    L[OFF_WTAB + 2 * tid] = a;
    L[OFF_WTAB + 2 * tid + 1] = bb;
  }
  __syncthreads();

  const int p  = blockIdx.x * 128 + (tid >> 1);
  const int hf = tid & 1;            // channel half: ch = hf*32 + [0,32)
  if (p >= U) return;                // no barriers after this point

  // ---- packed pillar record (pair loads same record; L1-coalesced)
  const float4* __restrict__ pdv = (const float4*)pd;
  const float4 A  = pdv[3 * (size_t)p];
  const float4 B  = pdv[3 * (size_t)p + 1];
  const float4 Cq = pdv[3 * (size_t)p + 2];
  const int cnt = unq_cnt[p];
  const bool has2 = (cnt >= 2);
  float vf0[5] = {A.x, A.y, A.z, A.w, B.x};
  float vf1[5] = {B.y, B.z, B.w, Cq.x, Cq.y};
#pragma unroll
  for (int i = 0; i < 5; ++i) vf1[i] = has2 ? vf1[i] : vf0[i];
  const int b0  = __builtin_bit_cast(int, Cq.z) & 31;
  const int b1e = has2 ? (__builtin_bit_cast(int, Cq.w) & 31) : 64;

  const float4* L4 = (const float4*)L;

  // ---- up-dimension MLP: this lane's 32 channels in registers
  float y0[32], y1[32];
#pragma unroll
  for (int cb = 0; cb < 8; ++cb) {
    float4 bb = L4[OFF_B2 / 4 + hf * 8 + cb];
    y0[4 * cb] = bb.x; y0[4 * cb + 1] = bb.y;
    y0[4 * cb + 2] = bb.z; y0[4 * cb + 3] = bb.w;
    y1[4 * cb] = bb.x; y1[4 * cb + 1] = bb.y;
    y1[4 * cb + 2] = bb.z; y1[4 * cb + 3] = bb.w;
  }
  const float4* w1p = L4 + OFF_W1B / 4;
  for (int j = 0; j < 32; ++j) {     // rolled; h inline (no h arrays)
    float4 wA = w1p[2 * j];
    float4 wB = w1p[2 * j + 1];
    float h0 = wB.y + vf0[0] * wA.x + vf0[1] * wA.y + vf0[2] * wA.z +
               vf0[3] * wA.w + vf0[4] * wB.x;
    float h1 = wB.y + vf1[0] * wA.x + vf1[1] * wA.y + vf1[2] * wA.z +
               vf1[3] * wA.w + vf1[4] * wB.x;
    h0 = fmaxf(h0, 0.0f);
    h1 = fmaxf(h1, 0.0f);
    const float4* wr = L4 + OFF_W2 / 4 + j * 16 + hf * 8;
#pragma unroll
    for (int cb = 0; cb < 8; ++cb) {
      float4 w = wr[cb];
      y0[4 * cb]     += h0 * w.x; y0[4 * cb + 1] += h0 * w.y;
      y0[4 * cb + 2] += h0 * w.z; y0[4 * cb + 3] += h0 * w.w;
      y1[4 * cb]     += h1 * w.x; y1[4 * cb + 1] += h1 * w.y;
      y1[4 * cb + 2] += h1 * w.z; y1[4 * cb + 3] += h1 * w.w;
    }
  }

  // ---- pooled stats + channel-MLP layer 1 partials (own 32 channels)
  float ha[16] = {0}, hm[16] = {0};
  const float kf = has2 ? 30.0f : 31.0f;   // 32 - nocc
  const float inv32 = 1.0f / 32.0f;
#pragma unroll
  for (int cb = 0; cb < 8; ++cb) {
    float4 c0q = L4[OFF_C0 / 4 + hf * 8 + cb];
    float c0a[4] = {c0q.x, c0q.y, c0q.z, c0q.w};
#pragma unroll
    for (int i = 0; i < 4; ++i) {
      int ch = 4 * cb + i;
      float c0v = c0a[i];
      float y1s = has2 ? y1[ch] : 0.0f;
      float sumy = y0[ch] + y1s;
      float maxy = fmaxf(y0[ch], y1[ch]);
      float avg = fmaf(c0v, kf, sumy) * inv32;
      float mxv = fmaxf(maxy, c0v);
      const float4* wp = L4 + OFF_WC1 / 4 + (hf * 32 + ch) * 4;
#pragma unroll
      for (int jb = 0; jb < 4; ++jb) {
        float4 w = wp[jb];
        ha[4 * jb]     += avg * w.x; ha[4 * jb + 1] += avg * w.y;
        ha[4 * jb + 2] += avg * w.z; ha[4 * jb + 3] += avg * w.w;
        hm[4 * jb]     += mxv * w.x; hm[4 * jb + 1] += mxv * w.y;
        hm[4 * jb + 2] += mxv * w.z; hm[4 * jb + 3] += mxv * w.w;
      }
    }
  }
  // pair-reduce partials, add bias, relu, combine pools
  float g[16];
#pragma unroll
  for (int jb = 0; jb < 4; ++jb) {
    float4 bb = L4[OFF_BC1 / 4 + jb];
    float bc[4] = {bb.x, bb.y, bb.z, bb.w};
#pragma unroll
    for (int i = 0; i < 4; ++i) {
      int j = 4 * jb + i;
      float sa = ha[j] + pairx(ha[j]) + bc[i];
      float sm = hm[j] + pairx(hm[j]) + bc[i];
      g[j] = fmaxf(sa, 0.0f) + fmaxf(sm, 0.0f);
    }
  }

  // ---- channel attention (stored) + bin-column partial reductions
  float attc[32];
  float sc = 0.0f, mc = -3.0e38f;
  float sy0 = 0.0f, my0 = -3.0e38f, sy1 = 0.0f, my1 = -3.0e38f;
#pragma unroll
  for (int cb = 0; cb < 8; ++cb) {
    float4 c0q  = L4[OFF_C0 / 4 + hf * 8 + cb];
    float4 bc2q = L4[OFF_BC2 / 4 + hf * 8 + cb];
    float c0a[4] = {c0q.x, c0q.y, c0q.z, c0q.w};
    float b2a[4] = {bc2q.x, bc2q.y, bc2q.z, bc2q.w};
#pragma unroll
    for (int i = 0; i < 4; ++i) {
      int ch = 4 * cb + i;
      const float4* wp = L4 + OFF_WC2T / 4 + (hf * 32 + ch) * 4;
      float4 wa = wp[0], wb = wp[1], wc = wp[2], wd = wp[3];
      float q0 = g[0] * wa.x + g[1] * wa.y + g[2] * wa.z + g[3] * wa.w;
      float q1 = g[4] * wb.x + g[5] * wb.y + g[6] * wb.z + g[7] * wb.w;
      float q2 = g[8] * wc.x + g[9] * wc.y + g[10] * wc.z + g[11] * wc.w;
      float q3 = g[12] * wd.x + g[13] * wd.y + g[14] * wd.z + g[15] * wd.w;
      float pre = 2.0f * b2a[i] + (q0 + q1) + (q2 + q3);
      float a = sgm(pre);
      attc[ch] = a;
      float c0v = c0a[i];
      float pc0 = a * c0v, py0 = a * y0[ch], py1 = a * y1[ch];
      sc += pc0;  mc = fmaxf(mc, pc0);
      sy0 += py0; my0 = fmaxf(my0, py0);
      sy1 += py1; my1 = fmaxf(my1, py1);
    }
  }
  sc += pairx(sc);   mc = fmaxf(mc, pairx(mc));
  sy0 += pairx(sy0); my0 = fmaxf(my0, pairx(my0));
  sy1 += pairx(sy1); my1 = fmaxf(my1, pairx(my1));

  // ---- analytic bin-attention conv: 16 bins per lane, pair-combined
  const float inv64 = 1.0f / 64.0f;
  const float Mn = sc * inv64, Mx = mc;
  const float dm0 = (sy0 - sc) * inv64, dx0 = my0 - mc;
  const float dm1 = (sy1 - sc) * inv64, dx1 = my1 - mc;
  const float bspr = bsp[0];
  const float2* Lws = (const float2*)(L + OFF_WSMX);
  const float2* Lwt = (const float2*)(L + OFF_WTAB);
  float maxE = -3.0e38f, minE = 3.0e38f, sv0 = -3.0e38f, sv1 = -3.0e38f;
  for (int bb = 0; bb < 16; ++bb) {
    int b = hf * 16 + bb;
    float2 ws = Lws[b];
    float acc = bspr + Mn * ws.x + Mx * ws.y;
    int k0 = b0 - b + 3;  k0 = ((unsigned)k0 <= 6u) ? k0 : 7;
    int k1 = b1e - b + 3; k1 = ((unsigned)k1 <= 6u) ? k1 : 7;
    float2 w0 = Lwt[k0];
    float2 w1v = Lwt[k1];
    acc += dm0 * w0.x + dx0 * w0.y + dm1 * w1v.x + dx1 * w1v.y;
    bool o0 = (b == b0), o1 = (b == b1e);
    bool oc = o0 || o1;
    maxE = fmaxf(maxE, oc ? -3.0e38f : acc);
    minE = fminf(minE, oc ?  3.0e38f : acc);
    sv0 = o0 ? acc : sv0;
    sv1 = o1 ? acc : sv1;
  }
  maxE = fmaxf(maxE, pairx(maxE));
  minE = fminf(minE, pairx(minE));
  sv0  = fmaxf(sv0, pairx(sv0));    // exactly one lane found it
  sv1  = fmaxf(sv1, pairx(sv1));
  const float sig0 = sgm(sv0);
  const float sig1 = has2 ? sgm(sv1) : sig0;
  const float sEv = sgm(maxE), sIv = sgm(minE);

  // ---- epilogue: final max over bins, store (wave covers 8KB contiguous)
  float4* outv = (float4*)(out + (size_t)p * CO + hf * 32);
  float* __restrict__ omask = out + (size_t)U * CO;
#pragma unroll
  for (int cb = 0; cb < 8; ++cb) {
    float4 c0q = L4[OFF_C0 / 4 + hf * 8 + cb];
    float c0a[4] = {c0q.x, c0q.y, c0q.z, c0q.w};
    float rr[4];
#pragma unroll
    for (int i = 0; i < 4; ++i) {
      int ch = 4 * cb + i;
      float c0v = c0a[i];
      float sel = (c0v >= 0.0f) ? sEv : sIv;
      float m = fmaxf(fmaxf(y0[ch] * sig0, y1[ch] * sig1), c0v * sel);
      rr[i] = attc[ch] * m;
    }
    float4 r;
    r.x = rr[0]; r.y = rr[1]; r.z = rr[2]; r.w = rr[3];
    outv[cb] = r;
  }
  if (hf == 0) omask[p] = has2 ? 1.0f : 0.0f;
}

extern "C" void kernel_launch(void* const* d_in, const int* in_sizes, int n_in,
                              void* d_out, int out_size, void* d_ws, size_t ws_size,
                              hipStream_t stream) {
  const float* vf      = (const float*)d_in[0];
  const int*   vcoord  = (const int*)d_in[1];
  // d_in[2] = unq_coords (unused: identity)
  const int*   unq_inv = (const int*)d_in[3];
  const int*   unq_cnt = (const int*)d_in[4];
  const float* W1  = (const float*)d_in[5];
  const float* b1  = (const float*)d_in[6];
  const float* W2  = (const float*)d_in[7];
  const float* b2  = (const float*)d_in[8];
  const float* Wc1 = (const float*)d_in[9];
  const float* bc1 = (const float*)d_in[10];
  const float* Wc2 = (const float*)d_in[11];
  const float* bc2 = (const float*)d_in[12];
  const float* Wsp = (const float*)d_in[13];
  const float* bsp = (const float*)d_in[14];

  const int N = in_sizes[3];   // voxels
  const int U = in_sizes[4];   // pillars

  float* pd = (float*)d_ws;    // 12 floats per pillar (4.8 MB @ U=100k)

  pack_kernel<<<(N + 255) / 256, 256, 0, stream>>>(vf, vcoord, unq_inv, pd, N);

  const int blocks = (U + 127) / 128;   // 2 threads per pillar
  cbam_kernel<<<blocks, 256, 0, stream>>>(
      pd, unq_cnt, W1, b1, W2, b2, Wc1, bc1, Wc2, bc2,
      Wsp, bsp, (float*)d_out, U);
}